// Round 14
// baseline (132.157 us; speedup 1.0000x reference)
//
#include <hip/hip_runtime.h>
#include <math.h>

#define S_LEN 4096
#define DMODEL 512
#define NHEAD 8
#define E_ELEMS ((size_t)8192 * 512)
#define QSCALE 0.18033688f   // 0.125 * log2(e): folded into wq/bq; exp2(S') = exp(S/8)

typedef __attribute__((ext_vector_type(8))) short bf16x8;
typedef __attribute__((ext_vector_type(4))) float f32x4;
typedef __attribute__((ext_vector_type(16))) float f32x16;
typedef unsigned short u16;
typedef unsigned int u32;

__device__ __forceinline__ u16 f2bf(float f) {              // RNE fp32 -> bf16
    u32 u = __float_as_uint(f);
    u += 0x7FFFu + ((u >> 16) & 1u);
    return (u16)(u >> 16);
}
__device__ __forceinline__ float bf2f(u16 h) {
    return __uint_as_float((u32)h << 16);
}

#define MFMA16(a, b, c) __builtin_amdgcn_mfma_f32_16x16x32_bf16((a), (b), (c), 0, 0, 0)
#define MFMA32(a, b, c) __builtin_amdgcn_mfma_f32_32x32x16_bf16((a), (b), (c), 0, 0, 0)

// ---------------------------------------------------------------------------
// Prepass (single kernel): x -> bf16 (blocks 0..4095); weights -> bf16 with
// wq pre-scaled by QSCALE (blocks 4096..4351).
// ---------------------------------------------------------------------------
__global__ __launch_bounds__(256) void cvt_all(
    const float* __restrict__ x,
    const float* __restrict__ wq, const float* __restrict__ wk,
    const float* __restrict__ wv, const float* __restrict__ wo,
    u16* __restrict__ xbf, u16* __restrict__ oq, u16* __restrict__ ok,
    u16* __restrict__ ov, u16* __restrict__ oo)
{
    const int bid = blockIdx.x;
    if (bid < 4096) {
        const int i = bid * 256 + threadIdx.x;
        const float4 v = ((const float4*)x)[i];
        uint2 hp;
        hp.x = (u32)f2bf(v.x) | ((u32)f2bf(v.y) << 16);
        hp.y = (u32)f2bf(v.z) | ((u32)f2bf(v.w) << 16);
        ((uint2*)xbf)[i] = hp;
    } else {
        const int i = (bid - 4096) * 256 + threadIdx.x;   // 0..65535
        {
            const float4 v = ((const float4*)wq)[i];
            uint2 hp;
            hp.x = (u32)f2bf(v.x * QSCALE) | ((u32)f2bf(v.y * QSCALE) << 16);
            hp.y = (u32)f2bf(v.z * QSCALE) | ((u32)f2bf(v.w * QSCALE) << 16);
            ((uint2*)oq)[i] = hp;
        }
        {
            const float4 v = ((const float4*)wk)[i];
            uint2 hp;
            hp.x = (u32)f2bf(v.x) | ((u32)f2bf(v.y) << 16);
            hp.y = (u32)f2bf(v.z) | ((u32)f2bf(v.w) << 16);
            ((uint2*)ok)[i] = hp;
        }
        {
            const float4 v = ((const float4*)wv)[i];
            uint2 hp;
            hp.x = (u32)f2bf(v.x) | ((u32)f2bf(v.y) << 16);
            hp.y = (u32)f2bf(v.z) | ((u32)f2bf(v.w) << 16);
            ((uint2*)ov)[i] = hp;
        }
        {
            const float4 v = ((const float4*)wo)[i];
            uint2 hp;
            hp.x = (u32)f2bf(v.x) | ((u32)f2bf(v.y) << 16);
            hp.y = (u32)f2bf(v.z) | ((u32)f2bf(v.w) << 16);
            ((uint2*)oo)[i] = hp;
        }
    }
}

// ---------------------------------------------------------------------------
// proj2: 128x128-tile GEMM, BK=64, global_load_lds staging with pre-swizzled
// source, 4 waves in 2x2, 32 MFMA16 per wave per k-step.  C = A @ W^T + bias.
// MODE 0: z in {0,1,2} picks Q/K/V weights; Q,K -> [bh][s][64] bf16;
//         V (z=2) -> transposed [bh][64][s] via two-pass LDS transpose.
// MODE 1: dense fp32 [8192][512] out (final projection).
// ---------------------------------------------------------------------------
template<int MODE>
__global__ __launch_bounds__(256) void proj2_kernel(
    const u16* __restrict__ Abf,
    const u16* __restrict__ W0, const float* __restrict__ Bi0,
    const u16* __restrict__ W1, const float* __restrict__ Bi1,
    const u16* __restrict__ W2, const float* __restrict__ Bi2,
    u16* __restrict__ Qo, u16* __restrict__ Ko, u16* __restrict__ Vt,
    float* __restrict__ Out)
{
    __shared__ __align__(16) u16 sm[18432];   // staging 32 KB; z=2 scr 36.9 KB
    u16* As = sm;
    u16* Bs = sm + 8192;

    const int tid = threadIdx.x;
    const int w = tid >> 6, l = tid & 63, g = (l >> 4), c = l & 15;
    const int wr = w >> 1, wc = w & 1;
    const int bm = blockIdx.x * 128;
    const int n0 = blockIdx.y * 128;
    const int z = (MODE == 0) ? blockIdx.z : 0;
    const u16* W   = (z == 0) ? W0 : (z == 1) ? W1 : W2;
    const float* Bi = (z == 0) ? Bi0 : (z == 1) ? Bi1 : Bi2;
    const float bsc = (MODE == 0 && z == 0) ? QSCALE : 1.0f;

    const int sr = l >> 3;        // 0..7 row within group
    const int slot = l & 7;       // 16B slot within row

    f32x4 acc[4][4];
    #pragma unroll
    for (int i = 0; i < 4; ++i)
        #pragma unroll
        for (int j = 0; j < 4; ++j) acc[i][j] = (f32x4){0.f, 0.f, 0.f, 0.f};

    #pragma unroll 1
    for (int kt = 0; kt < 8; ++kt) {
        const int k0 = kt * 64;
        __syncthreads();
        #pragma unroll
        for (int i = 0; i < 4; ++i) {
            const int row = i * 32 + w * 8 + sr;
            const int scol = (slot ^ (row & 7)) * 8;
            __builtin_amdgcn_global_load_lds(
                Abf + (size_t)(bm + row) * DMODEL + k0 + scol,
                As + (i * 32 + w * 8) * 64, 16, 0, 0);
            __builtin_amdgcn_global_load_lds(
                W + (size_t)(n0 + row) * DMODEL + k0 + scol,
                Bs + (i * 32 + w * 8) * 64, 16, 0, 0);
        }
        __syncthreads();

        #pragma unroll
        for (int kc = 0; kc < 2; ++kc) {
            bf16x8 a[4], b[4];
            #pragma unroll
            for (int mf = 0; mf < 4; ++mf) {
                const int ra = wr * 64 + mf * 16 + c;
                a[mf] = *(const bf16x8*)(As + ra * 64 + (((kc * 4 + g) ^ (ra & 7)) * 8));
            }
            #pragma unroll
            for (int nf = 0; nf < 4; ++nf) {
                const int rb = wc * 64 + nf * 16 + c;
                b[nf] = *(const bf16x8*)(Bs + rb * 64 + (((kc * 4 + g) ^ (rb & 7)) * 8));
            }
            #pragma unroll
            for (int mf = 0; mf < 4; ++mf)
                #pragma unroll
                for (int nf = 0; nf < 4; ++nf)
                    acc[mf][nf] = MFMA16(a[mf], b[nf], acc[mf][nf]);
        }
    }

    if (MODE == 0 && z == 2) {
        // V: two-pass LDS transpose (one head per pass) -> V^T [bh][64][4096]
        __syncthreads();
        float* scr = (float*)sm;              // [128][72] fp32 = 36.9 KB
        const int d = tid & 63, sb = tid >> 6;
        const int b = bm >> 12;
        #pragma unroll
        for (int pass = 0; pass < 2; ++pass) {
            if (wc == pass) {
                #pragma unroll
                for (int mf = 0; mf < 4; ++mf)
                    #pragma unroll
                    for (int nf = 0; nf < 4; ++nf) {
                        const float bias = Bi[n0 + pass * 64 + nf * 16 + c];
                        #pragma unroll
                        for (int r = 0; r < 4; ++r)
                            scr[(wr * 64 + mf * 16 + 4 * g + r) * 72 + nf * 16 + c] =
                                acc[mf][nf][r] + bias;
                    }
            }
            __syncthreads();
            const int hh = (n0 >> 6) + pass;
            const size_t obase =
                ((size_t)((b * NHEAD + hh) * 64 + d)) * S_LEN + (bm & (S_LEN - 1)) + sb * 32;
            u16 th[32];
            #pragma unroll
            for (int j = 0; j < 32; ++j)
                th[j] = f2bf(scr[(sb * 32 + j) * 72 + d]);
            #pragma unroll
            for (int q4 = 0; q4 < 4; ++q4)
                *(uint4*)(Vt + obase + q4 * 8) = *(const uint4*)&th[q4 * 8];
            __syncthreads();
        }
        return;
    }

    #pragma unroll
    for (int mf = 0; mf < 4; ++mf)
        #pragma unroll
        for (int nf = 0; nf < 4; ++nf) {
            const int n = n0 + wc * 64 + nf * 16 + c;
            const float bias = Bi[n] * bsc;
            #pragma unroll
            for (int r = 0; r < 4; ++r) {
                const int m = bm + wr * 64 + mf * 16 + 4 * g + r;
                const float v = acc[mf][nf][r] + bias;
                if (MODE == 1) {
                    Out[(size_t)m * DMODEL + n] = v;
                } else {
                    const int b = m >> 12, s = m & (S_LEN - 1);
                    const int hh = n >> 6, dd = n & 63;
                    const size_t o = ((size_t)((b * NHEAD + hh) * S_LEN + s)) * 64 + dd;
                    if (z == 0) Qo[o] = f2bf(v);
                    else        Ko[o] = f2bf(v);
                }
            }
        }
}

// ---------------------------------------------------------------------------
// Flash attention v13: R13's ring-3 counted-vmcnt pipeline + L-via-MFMA.
// The 64 per-tile lsum VALU adds are replaced by 8 MFMA32 with an all-ones
// B operand (Lacc = P . 1): row-sums land in the accumulator C-layout, the
// kv-half shfl dies, and the VALU pipe (measured busiest at 47%) sheds ~30%.
// V fragments for each kv-half are loaded before the exp2/pack section so
// their LDS latency overlaps the VALU work.
// Grid kv-split-4: 1024 blocks x 4 waves, 64 q/wave, 16 KV-tiles of 64.
// ---------------------------------------------------------------------------
__global__ __launch_bounds__(256, 2) void attn_kernel(
    const u16* __restrict__ Qb, const u16* __restrict__ Kb,
    const u16* __restrict__ Vt, u16* __restrict__ OpB, float* __restrict__ Lp)
{
    __shared__ __align__(16) u16 sm[24576];   // 48 KB: 3 bufs x (K 8KB + V 8KB)

    const int tid = threadIdx.x;
    const int w = tid >> 6, l = tid & 63;
    const int r0 = l & 31, hi = l >> 5;

    // XCD swizzle: 1024 % 8 == 0, bijective
    const int f = blockIdx.x;
    const int wg = (f & 7) * 128 + (f >> 3);
    const int bh = wg >> 6, kvq = (wg >> 4) & 3, qb = wg & 15;
    const int b = bh >> 3, h = bh & 7;

    const size_t hoff = (size_t)bh * S_LEN * 64;
    const int qw = qb * 256 + w * 64;          // this wave's 64 q-rows
    const int kv0 = kvq * 1024;                // this block's kv-quarter

    // Q fragments (B-operand), 2 per wave: lane: col q = qf*32+r0, k = hi*8+e
    bf16x8 qf[2][4];
    #pragma unroll
    for (int qfi = 0; qfi < 2; ++qfi)
        #pragma unroll
        for (int kc = 0; kc < 4; ++kc)
            qf[qfi][kc] = *(const bf16x8*)(Qb + hoff +
                (size_t)(qw + qfi * 32 + r0) * 64 + kc * 16 + hi * 8);

    // all-ones bf16 fragment (B operand of the L row-sum MFMA)
    const short ONE = (short)0x3F80;
    const bf16x8 onesf = {ONE, ONE, ONE, ONE, ONE, ONE, ONE, ONE};

    // swizzled LDS fragment offsets
    const int rbase = r0 * 64;
    int soff[4];
    #pragma unroll
    for (int j = 0; j < 4; ++j) soff[j] = ((2 * j + hi) ^ (r0 & 7)) * 8;

    // staging sources (per lane, pre-swizzled): 4 waves stage 64 rows
    const int srow0 = w * 16 + (l >> 3);
    const int slot  = l & 7;
    const int srow1 = srow0 + 8;
    const u16* srcK0 = Kb + hoff + (size_t)(kv0 + srow0) * 64 + ((slot ^ (srow0 & 7)) * 8);
    const u16* srcK1 = Kb + hoff + (size_t)(kv0 + srow1) * 64 + ((slot ^ (srow1 & 7)) * 8);
    const u16* srcV0 = Vt + ((size_t)bh * 64 + srow0) * S_LEN + kv0 + ((slot ^ (srow0 & 7)) * 8);
    const u16* srcV1 = Vt + ((size_t)bh * 64 + srow1) * S_LEN + kv0 + ((slot ^ (srow1 & 7)) * 8);

#define STAGE(bufb, t) do {                                                        \
        u16* kb_ = sm + (bufb) * 8192 + w * 1024;                                  \
        u16* vb_ = kb_ + 4096;                                                     \
        __builtin_amdgcn_global_load_lds(srcK0 + (size_t)(t) * 4096, kb_,       16, 0, 0); \
        __builtin_amdgcn_global_load_lds(srcK1 + (size_t)(t) * 4096, kb_ + 512, 16, 0, 0); \
        __builtin_amdgcn_global_load_lds(srcV0 + (size_t)(t) * 64,   vb_,       16, 0, 0); \
        __builtin_amdgcn_global_load_lds(srcV1 + (size_t)(t) * 64,   vb_ + 512, 16, 0, 0); \
    } while (0)

#define ZERO16 {0.f,0.f,0.f,0.f,0.f,0.f,0.f,0.f,0.f,0.f,0.f,0.f,0.f,0.f,0.f,0.f}
    f32x16 o00 = ZERO16, o01 = ZERO16, o10 = ZERO16, o11 = ZERO16;
    f32x16 lAacc = ZERO16, lBacc = ZERO16;

    // compute one 64-kv tile from LDS buffers
    auto compute_tile = [&](const u16* Kb_s, const u16* Vb_s) {
        #pragma unroll
        for (int kvf = 0; kvf < 2; ++kvf) {
            f32x16 sA = ZERO16, sB = ZERO16;
            __builtin_amdgcn_s_setprio(1);
            #pragma unroll
            for (int kc = 0; kc < 4; ++kc) {
                const bf16x8 k = *(const bf16x8*)(Kb_s + kvf * 2048 + rbase + soff[kc]);
                sA = MFMA32(k, qf[0][kc], sA);
                sB = MFMA32(k, qf[1][kc], sB);
            }
            __builtin_amdgcn_s_setprio(0);

            // hoist this kv-half's V fragments (LDS latency overlaps exp2/pack)
            const bf16x8 v00 = *(const bf16x8*)(Vb_s + rbase + soff[kvf * 2 + 0]);
            const bf16x8 v01 = *(const bf16x8*)(Vb_s + 2048 + rbase + soff[kvf * 2 + 0]);
            const bf16x8 v10 = *(const bf16x8*)(Vb_s + rbase + soff[kvf * 2 + 1]);
            const bf16x8 v11 = *(const bf16x8*)(Vb_s + 2048 + rbase + soff[kvf * 2 + 1]);

            #pragma unroll
            for (int r = 0; r < 16; ++r) {
                sA[r] = __builtin_amdgcn_exp2f(sA[r]);
                sB[r] = __builtin_amdgcn_exp2f(sB[r]);
            }

            #pragma unroll
            for (int hf = 0; hf < 2; ++hf) {
                const int rb = hf * 8;
                u32 x0, y0, x1, y1;
                asm("v_cvt_pk_bf16_f32 %0, %1, %2" : "=v"(x0) : "v"(sA[rb+0]), "v"(sA[rb+1]));
                asm("v_cvt_pk_bf16_f32 %0, %1, %2" : "=v"(y0) : "v"(sA[rb+4]), "v"(sA[rb+5]));
                asm("v_cvt_pk_bf16_f32 %0, %1, %2" : "=v"(x1) : "v"(sA[rb+2]), "v"(sA[rb+3]));
                asm("v_cvt_pk_bf16_f32 %0, %1, %2" : "=v"(y1) : "v"(sA[rb+6]), "v"(sA[rb+7]));
                asm volatile("v_permlane32_swap_b32 %0, %1" : "+v"(x0), "+v"(y0));
                asm volatile("v_permlane32_swap_b32 %0, %1" : "+v"(x1), "+v"(y1));
                union { u32 u[4]; bf16x8 v; } PA;
                PA.u[0] = x0; PA.u[1] = x1; PA.u[2] = y0; PA.u[3] = y1;
                asm("v_cvt_pk_bf16_f32 %0, %1, %2" : "=v"(x0) : "v"(sB[rb+0]), "v"(sB[rb+1]));
                asm("v_cvt_pk_bf16_f32 %0, %1, %2" : "=v"(y0) : "v"(sB[rb+4]), "v"(sB[rb+5]));
                asm("v_cvt_pk_bf16_f32 %0, %1, %2" : "=v"(x1) : "v"(sB[rb+2]), "v"(sB[rb+3]));
                asm("v_cvt_pk_bf16_f32 %0, %1, %2" : "=v"(y1) : "v"(sB[rb+6]), "v"(sB[rb+7]));
                asm volatile("v_permlane32_swap_b32 %0, %1" : "+v"(x0), "+v"(y0));
                asm volatile("v_permlane32_swap_b32 %0, %1" : "+v"(x1), "+v"(y1));
                union { u32 u[4]; bf16x8 v; } PB;
                PB.u[0] = x0; PB.u[1] = x1; PB.u[2] = y0; PB.u[3] = y1;

                const bf16x8 v0 = hf ? v10 : v00;
                const bf16x8 v1 = hf ? v11 : v01;
                __builtin_amdgcn_s_setprio(1);
                o00 = MFMA32(PA.v, v0, o00);
                o01 = MFMA32(PA.v, v1, o01);
                o10 = MFMA32(PB.v, v0, o10);
                o11 = MFMA32(PB.v, v1, o11);
                lAacc = MFMA32(PA.v, onesf, lAacc);   // row-sums of P (L accum)
                lBacc = MFMA32(PB.v, onesf, lBacc);
                __builtin_amdgcn_s_setprio(0);
            }
        }
    };

    STAGE(0, 0);
    STAGE(1, 1);

    #pragma unroll 1
    for (int t = 0; t < 15; ++t) {
        // tile t's 4 glds complete (4 newest = tile t+1's stay in flight)
        asm volatile("s_waitcnt vmcnt(4)" ::: "memory");
        __builtin_amdgcn_s_barrier();            // raw: no vmcnt(0) drain
        __builtin_amdgcn_sched_barrier(0);       // no ds_read hoist above barrier
        if (t < 14) STAGE((t + 2) % 3, t + 2);   // 2-deep prefetch
        const u16* Kb_s = sm + (t % 3) * 8192;
        compute_tile(Kb_s, Kb_s + 4096);
    }
    {
        asm volatile("s_waitcnt vmcnt(0)" ::: "memory");
        __builtin_amdgcn_s_barrier();
        __builtin_amdgcn_sched_barrier(0);
        const u16* Kb_s = sm + (15 % 3) * 8192;
        compute_tile(Kb_s, Kb_s + 4096);
    }
#undef STAGE

    // epilogue: L from Lacc C-layout (row=(r&3)+8*(r>>2)+4*hi, cols identical).
    // Lanes 0 (hi=0) and 32 (hi=1) hold complementary q-row sets.
    if (r0 == 0) {
        const size_t lb = ((size_t)kvq * 16 + bh) * S_LEN + qw;
        #pragma unroll
        for (int r = 0; r < 16; ++r) {
            const int q = (r & 3) + 8 * (r >> 2) + 4 * hi;
            Lp[lb + q]      = lAacc[r];
            Lp[lb + 32 + q] = lBacc[r];
        }
    }

    u16* Ob = OpB + (size_t)kvq * E_ELEMS + (size_t)b * S_LEN * DMODEL;
    #pragma unroll
    for (int qfi = 0; qfi < 2; ++qfi)
        #pragma unroll
        for (int df = 0; df < 2; ++df) {
            #pragma unroll
            for (int r = 0; r < 16; ++r) {
                const float ov = qfi ? (df ? o11[r] : o10[r]) : (df ? o01[r] : o00[r]);
                const int q = qfi * 32 + (r & 3) + 8 * (r >> 2) + 4 * hi;
                Ob[(size_t)(qw + q) * DMODEL + h * 64 + df * 32 + r0] = f2bf(ov);
            }
        }
}

// ---------------------------------------------------------------------------
// Combine: AO_bf16 = (sum of 4 bf16 O-quarters) / (sum of 4 L)
// ---------------------------------------------------------------------------
__global__ __launch_bounds__(256) void combine_kernel(
    const u16* __restrict__ Op, const float* __restrict__ Lp,
    u16* __restrict__ A)
{
    const int i = blockIdx.x * 256 + threadIdx.x;   // 524288 chunks of 8
    const int m = i >> 6;                           // row 0..8191
    const int col = (i & 63) * 8;
    const int b = m >> 12, s = m & (S_LEN - 1), h = col >> 6;
    const int bh = b * 8 + h;

    float lt = 0.f;
    #pragma unroll
    for (int kq = 0; kq < 4; ++kq)
        lt += Lp[((size_t)kq * 16 + bh) * S_LEN + s];
    const float inv = 1.0f / lt;

    float acc[8] = {};
    #pragma unroll
    for (int kq = 0; kq < 4; ++kq) {
        const uint4 v = *(const uint4*)(Op + (size_t)kq * E_ELEMS + (size_t)m * DMODEL + col);
        const u16* p = (const u16*)&v;
        #pragma unroll
        for (int j = 0; j < 8; ++j) acc[j] += bf2f(p[j]);
    }
    u16 r[8];
    #pragma unroll
    for (int j = 0; j < 8; ++j) r[j] = f2bf(acc[j] * inv);
    *(uint4*)(A + (size_t)m * DMODEL + col) = *(const uint4*)r;
}

// ---------------------------------------------------------------------------
extern "C" void kernel_launch(void* const* d_in, const int* in_sizes, int n_in,
                              void* d_out, int out_size, void* d_ws, size_t ws_size,
                              hipStream_t stream)
{
    const float* x  = (const float*)d_in[0];
    const float* wq = (const float*)d_in[1];
    const float* bq = (const float*)d_in[2];
    const float* wk = (const float*)d_in[3];
    const float* bk = (const float*)d_in[4];
    const float* wv = (const float*)d_in[5];
    const float* bv = (const float*)d_in[6];
    const float* wo = (const float*)d_in[7];
    const float* bo = (const float*)d_in[8];

    u16* ws = (u16*)d_ws;
    const size_t E = E_ELEMS;
    u16* xbf  = ws;                 // [8192][512]; reused as AO bf16 after combine
    u16* Qbf  = ws + E;             // [bh][s][64]  (pre-scaled)
    u16* Kbf  = ws + 2 * E;         // [bh][s][64]
    u16* Vtbf = ws + 3 * E;         // [bh][64][s]
    u16* wqbf = ws + 4 * E;         // 4 x [512][512]
    u16* wkbf = wqbf + DMODEL * DMODEL;
    u16* wvbf = wkbf + DMODEL * DMODEL;
    u16* wobf = wvbf + DMODEL * DMODEL;
    u16* OpB  = wobf + DMODEL * DMODEL;        // [4][8192][512] bf16 (33.5 MB)
    float* Lp = (float*)(OpB + 4 * E);         // [4][16][4096] f32 (1 MB)

    cvt_all<<<dim3(4352), 256, 0, stream>>>(
        x, wq, wk, wv, wo, xbf, wqbf, wkbf, wvbf, wobf);

    proj2_kernel<0><<<dim3(64, 4, 3), 256, 0, stream>>>(
        xbf, wqbf, bq, wkbf, bk, wvbf, bv, Qbf, Kbf, Vtbf, nullptr);

    attn_kernel<<<dim3(1024), 256, 0, stream>>>(Qbf, Kbf, Vtbf, OpB, Lp);

    combine_kernel<<<dim3(2048), 256, 0, stream>>>(OpB, Lp, xbf);

    proj2_kernel<1><<<dim3(64, 4, 1), 256, 0, stream>>>(
        xbf, wobf, bo, nullptr, nullptr, nullptr, nullptr,
        nullptr, nullptr, nullptr, (float*)d_out);
}

// Round 15
// 126.494 us; speedup vs baseline: 1.0448x; 1.0448x over previous
//
#include <hip/hip_runtime.h>
#include <math.h>

#define S_LEN 4096
#define DMODEL 512
#define NHEAD 8
#define E_ELEMS ((size_t)8192 * 512)
#define QSCALE 0.18033688f   // 0.125 * log2(e): folded into wq/bq; exp2(S') = exp(S/8)

typedef __attribute__((ext_vector_type(8))) short bf16x8;
typedef __attribute__((ext_vector_type(4))) float f32x4;
typedef __attribute__((ext_vector_type(16))) float f32x16;
typedef unsigned short u16;
typedef unsigned int u32;

__device__ __forceinline__ u16 f2bf(float f) {              // RNE fp32 -> bf16
    u32 u = __float_as_uint(f);
    u += 0x7FFFu + ((u >> 16) & 1u);
    return (u16)(u >> 16);
}
__device__ __forceinline__ float bf2f(u16 h) {
    return __uint_as_float((u32)h << 16);
}

#define MFMA16(a, b, c) __builtin_amdgcn_mfma_f32_16x16x32_bf16((a), (b), (c), 0, 0, 0)
#define MFMA32(a, b, c) __builtin_amdgcn_mfma_f32_32x32x16_bf16((a), (b), (c), 0, 0, 0)

// ---------------------------------------------------------------------------
// Prepass (single kernel): x -> bf16 (blocks 0..4095); weights -> bf16 with
// wq pre-scaled by QSCALE (blocks 4096..4351).
// ---------------------------------------------------------------------------
__global__ __launch_bounds__(256) void cvt_all(
    const float* __restrict__ x,
    const float* __restrict__ wq, const float* __restrict__ wk,
    const float* __restrict__ wv, const float* __restrict__ wo,
    u16* __restrict__ xbf, u16* __restrict__ oq, u16* __restrict__ ok,
    u16* __restrict__ ov, u16* __restrict__ oo)
{
    const int bid = blockIdx.x;
    if (bid < 4096) {
        const int i = bid * 256 + threadIdx.x;
        const float4 v = ((const float4*)x)[i];
        uint2 hp;
        hp.x = (u32)f2bf(v.x) | ((u32)f2bf(v.y) << 16);
        hp.y = (u32)f2bf(v.z) | ((u32)f2bf(v.w) << 16);
        ((uint2*)xbf)[i] = hp;
    } else {
        const int i = (bid - 4096) * 256 + threadIdx.x;   // 0..65535
        {
            const float4 v = ((const float4*)wq)[i];
            uint2 hp;
            hp.x = (u32)f2bf(v.x * QSCALE) | ((u32)f2bf(v.y * QSCALE) << 16);
            hp.y = (u32)f2bf(v.z * QSCALE) | ((u32)f2bf(v.w * QSCALE) << 16);
            ((uint2*)oq)[i] = hp;
        }
        {
            const float4 v = ((const float4*)wk)[i];
            uint2 hp;
            hp.x = (u32)f2bf(v.x) | ((u32)f2bf(v.y) << 16);
            hp.y = (u32)f2bf(v.z) | ((u32)f2bf(v.w) << 16);
            ((uint2*)ok)[i] = hp;
        }
        {
            const float4 v = ((const float4*)wv)[i];
            uint2 hp;
            hp.x = (u32)f2bf(v.x) | ((u32)f2bf(v.y) << 16);
            hp.y = (u32)f2bf(v.z) | ((u32)f2bf(v.w) << 16);
            ((uint2*)ov)[i] = hp;
        }
        {
            const float4 v = ((const float4*)wo)[i];
            uint2 hp;
            hp.x = (u32)f2bf(v.x) | ((u32)f2bf(v.y) << 16);
            hp.y = (u32)f2bf(v.z) | ((u32)f2bf(v.w) << 16);
            ((uint2*)oo)[i] = hp;
        }
    }
}

// ---------------------------------------------------------------------------
// proj2: 128x128-tile GEMM, BK=64, global_load_lds staging with pre-swizzled
// source, 4 waves in 2x2, 32 MFMA16 per wave per k-step.  C = A @ W^T + bias.
// MODE 0: z in {0,1,2} picks Q/K/V weights; Q,K -> [bh][s][64] bf16;
//         V (z=2) -> transposed [bh][64][s] via two-pass LDS transpose.
// MODE 1: dense fp32 [8192][512] out (final projection).
// ---------------------------------------------------------------------------
template<int MODE>
__global__ __launch_bounds__(256) void proj2_kernel(
    const u16* __restrict__ Abf,
    const u16* __restrict__ W0, const float* __restrict__ Bi0,
    const u16* __restrict__ W1, const float* __restrict__ Bi1,
    const u16* __restrict__ W2, const float* __restrict__ Bi2,
    u16* __restrict__ Qo, u16* __restrict__ Ko, u16* __restrict__ Vt,
    float* __restrict__ Out)
{
    __shared__ __align__(16) u16 sm[18432];   // staging 32 KB; z=2 scr 36.9 KB
    u16* As = sm;
    u16* Bs = sm + 8192;

    const int tid = threadIdx.x;
    const int w = tid >> 6, l = tid & 63, g = (l >> 4), c = l & 15;
    const int wr = w >> 1, wc = w & 1;
    const int bm = blockIdx.x * 128;
    const int n0 = blockIdx.y * 128;
    const int z = (MODE == 0) ? blockIdx.z : 0;
    const u16* W   = (z == 0) ? W0 : (z == 1) ? W1 : W2;
    const float* Bi = (z == 0) ? Bi0 : (z == 1) ? Bi1 : Bi2;
    const float bsc = (MODE == 0 && z == 0) ? QSCALE : 1.0f;

    const int sr = l >> 3;        // 0..7 row within group
    const int slot = l & 7;       // 16B slot within row

    f32x4 acc[4][4];
    #pragma unroll
    for (int i = 0; i < 4; ++i)
        #pragma unroll
        for (int j = 0; j < 4; ++j) acc[i][j] = (f32x4){0.f, 0.f, 0.f, 0.f};

    #pragma unroll 1
    for (int kt = 0; kt < 8; ++kt) {
        const int k0 = kt * 64;
        __syncthreads();
        #pragma unroll
        for (int i = 0; i < 4; ++i) {
            const int row = i * 32 + w * 8 + sr;
            const int scol = (slot ^ (row & 7)) * 8;
            __builtin_amdgcn_global_load_lds(
                Abf + (size_t)(bm + row) * DMODEL + k0 + scol,
                As + (i * 32 + w * 8) * 64, 16, 0, 0);
            __builtin_amdgcn_global_load_lds(
                W + (size_t)(n0 + row) * DMODEL + k0 + scol,
                Bs + (i * 32 + w * 8) * 64, 16, 0, 0);
        }
        __syncthreads();

        #pragma unroll
        for (int kc = 0; kc < 2; ++kc) {
            bf16x8 a[4], b[4];
            #pragma unroll
            for (int mf = 0; mf < 4; ++mf) {
                const int ra = wr * 64 + mf * 16 + c;
                a[mf] = *(const bf16x8*)(As + ra * 64 + (((kc * 4 + g) ^ (ra & 7)) * 8));
            }
            #pragma unroll
            for (int nf = 0; nf < 4; ++nf) {
                const int rb = wc * 64 + nf * 16 + c;
                b[nf] = *(const bf16x8*)(Bs + rb * 64 + (((kc * 4 + g) ^ (rb & 7)) * 8));
            }
            #pragma unroll
            for (int mf = 0; mf < 4; ++mf)
                #pragma unroll
                for (int nf = 0; nf < 4; ++nf)
                    acc[mf][nf] = MFMA16(a[mf], b[nf], acc[mf][nf]);
        }
    }

    if (MODE == 0 && z == 2) {
        // V: two-pass LDS transpose (one head per pass) -> V^T [bh][64][4096]
        __syncthreads();
        float* scr = (float*)sm;              // [128][72] fp32 = 36.9 KB
        const int d = tid & 63, sb = tid >> 6;
        const int b = bm >> 12;
        #pragma unroll
        for (int pass = 0; pass < 2; ++pass) {
            if (wc == pass) {
                #pragma unroll
                for (int mf = 0; mf < 4; ++mf)
                    #pragma unroll
                    for (int nf = 0; nf < 4; ++nf) {
                        const float bias = Bi[n0 + pass * 64 + nf * 16 + c];
                        #pragma unroll
                        for (int r = 0; r < 4; ++r)
                            scr[(wr * 64 + mf * 16 + 4 * g + r) * 72 + nf * 16 + c] =
                                acc[mf][nf][r] + bias;
                    }
            }
            __syncthreads();
            const int hh = (n0 >> 6) + pass;
            const size_t obase =
                ((size_t)((b * NHEAD + hh) * 64 + d)) * S_LEN + (bm & (S_LEN - 1)) + sb * 32;
            u16 th[32];
            #pragma unroll
            for (int j = 0; j < 32; ++j)
                th[j] = f2bf(scr[(sb * 32 + j) * 72 + d]);
            #pragma unroll
            for (int q4 = 0; q4 < 4; ++q4)
                *(uint4*)(Vt + obase + q4 * 8) = *(const uint4*)&th[q4 * 8];
            __syncthreads();
        }
        return;
    }

    #pragma unroll
    for (int mf = 0; mf < 4; ++mf)
        #pragma unroll
        for (int nf = 0; nf < 4; ++nf) {
            const int n = n0 + wc * 64 + nf * 16 + c;
            const float bias = Bi[n] * bsc;
            #pragma unroll
            for (int r = 0; r < 4; ++r) {
                const int m = bm + wr * 64 + mf * 16 + 4 * g + r;
                const float v = acc[mf][nf][r] + bias;
                if (MODE == 1) {
                    Out[(size_t)m * DMODEL + n] = v;
                } else {
                    const int b = m >> 12, s = m & (S_LEN - 1);
                    const int hh = n >> 6, dd = n & 63;
                    const size_t o = ((size_t)((b * NHEAD + hh) * S_LEN + s)) * 64 + dd;
                    if (z == 0) Qo[o] = f2bf(v);
                    else        Ko[o] = f2bf(v);
                }
            }
        }
}

// ---------------------------------------------------------------------------
// Flash attention v14: R13's ring-3 counted-vmcnt loop (best measured: 79.5us,
// 864 TF) at kv-split-2.  Occupancy is register-tier-pinned at 2 blocks/CU
// regardless of grid, so 512 blocks x 32 tiles gives identical residency
// (one clean pass) while halving partial-O traffic and combine cost.
// Grid: 512 blocks (16 bh x 2 kvh x 16 qb) x 4 waves, 64 q/wave.
// ---------------------------------------------------------------------------
__global__ __launch_bounds__(256, 2) void attn_kernel(
    const u16* __restrict__ Qb, const u16* __restrict__ Kb,
    const u16* __restrict__ Vt, u16* __restrict__ OpB, float* __restrict__ Lp)
{
    __shared__ __align__(16) u16 sm[24576];   // 48 KB: 3 bufs x (K 8KB + V 8KB)

    const int tid = threadIdx.x;
    const int w = tid >> 6, l = tid & 63;
    const int r0 = l & 31, hi = l >> 5;

    // XCD swizzle: 512 % 8 == 0, bijective
    const int f = blockIdx.x;
    const int wg = (f & 7) * 64 + (f >> 3);
    const int bh = wg >> 5, kvh = (wg >> 4) & 1, qb = wg & 15;
    const int b = bh >> 3, h = bh & 7;

    const size_t hoff = (size_t)bh * S_LEN * 64;
    const int qw = qb * 256 + w * 64;          // this wave's 64 q-rows
    const int kv0 = kvh * 2048;                // this block's kv-half

    // Q fragments (B-operand), 2 per wave: lane: col q = qf*32+r0, k = hi*8+e
    bf16x8 qf[2][4];
    #pragma unroll
    for (int qfi = 0; qfi < 2; ++qfi)
        #pragma unroll
        for (int kc = 0; kc < 4; ++kc)
            qf[qfi][kc] = *(const bf16x8*)(Qb + hoff +
                (size_t)(qw + qfi * 32 + r0) * 64 + kc * 16 + hi * 8);

    // swizzled LDS fragment offsets
    const int rbase = r0 * 64;
    int soff[4];
    #pragma unroll
    for (int j = 0; j < 4; ++j) soff[j] = ((2 * j + hi) ^ (r0 & 7)) * 8;

    // staging sources (per lane, pre-swizzled): 4 waves stage 64 rows
    const int srow0 = w * 16 + (l >> 3);
    const int slot  = l & 7;
    const int srow1 = srow0 + 8;
    const u16* srcK0 = Kb + hoff + (size_t)(kv0 + srow0) * 64 + ((slot ^ (srow0 & 7)) * 8);
    const u16* srcK1 = Kb + hoff + (size_t)(kv0 + srow1) * 64 + ((slot ^ (srow1 & 7)) * 8);
    const u16* srcV0 = Vt + ((size_t)bh * 64 + srow0) * S_LEN + kv0 + ((slot ^ (srow0 & 7)) * 8);
    const u16* srcV1 = Vt + ((size_t)bh * 64 + srow1) * S_LEN + kv0 + ((slot ^ (srow1 & 7)) * 8);

#define STAGE(bufb, t) do {                                                        \
        u16* kb_ = sm + (bufb) * 8192 + w * 1024;                                  \
        u16* vb_ = kb_ + 4096;                                                     \
        __builtin_amdgcn_global_load_lds(srcK0 + (size_t)(t) * 4096, kb_,       16, 0, 0); \
        __builtin_amdgcn_global_load_lds(srcK1 + (size_t)(t) * 4096, kb_ + 512, 16, 0, 0); \
        __builtin_amdgcn_global_load_lds(srcV0 + (size_t)(t) * 64,   vb_,       16, 0, 0); \
        __builtin_amdgcn_global_load_lds(srcV1 + (size_t)(t) * 64,   vb_ + 512, 16, 0, 0); \
    } while (0)

#define ZERO16 {0.f,0.f,0.f,0.f,0.f,0.f,0.f,0.f,0.f,0.f,0.f,0.f,0.f,0.f,0.f,0.f}
    f32x16 o00 = ZERO16, o01 = ZERO16, o10 = ZERO16, o11 = ZERO16;
    float lA = 0.f, lB = 0.f;

    // compute one 64-kv tile from LDS buffers (R13 body, byte-identical)
    auto compute_tile = [&](const u16* Kb_s, const u16* Vb_s) {
        #pragma unroll
        for (int kvf = 0; kvf < 2; ++kvf) {
            f32x16 sA = ZERO16, sB = ZERO16;
            __builtin_amdgcn_s_setprio(1);
            #pragma unroll
            for (int kc = 0; kc < 4; ++kc) {
                const bf16x8 k = *(const bf16x8*)(Kb_s + kvf * 2048 + rbase + soff[kc]);
                sA = MFMA32(k, qf[0][kc], sA);
                sB = MFMA32(k, qf[1][kc], sB);
            }
            __builtin_amdgcn_s_setprio(0);

            #pragma unroll
            for (int r = 0; r < 16; ++r) {
                sA[r] = __builtin_amdgcn_exp2f(sA[r]);
                sB[r] = __builtin_amdgcn_exp2f(sB[r]);
            }
            #pragma unroll
            for (int r = 0; r < 16; ++r) { lA += sA[r]; lB += sB[r]; }

            #pragma unroll
            for (int hf = 0; hf < 2; ++hf) {
                const int rb = hf * 8;
                const int idx = kvf * 2 + hf;
                u32 x0, y0, x1, y1;
                asm("v_cvt_pk_bf16_f32 %0, %1, %2" : "=v"(x0) : "v"(sA[rb+0]), "v"(sA[rb+1]));
                asm("v_cvt_pk_bf16_f32 %0, %1, %2" : "=v"(y0) : "v"(sA[rb+4]), "v"(sA[rb+5]));
                asm("v_cvt_pk_bf16_f32 %0, %1, %2" : "=v"(x1) : "v"(sA[rb+2]), "v"(sA[rb+3]));
                asm("v_cvt_pk_bf16_f32 %0, %1, %2" : "=v"(y1) : "v"(sA[rb+6]), "v"(sA[rb+7]));
                asm volatile("v_permlane32_swap_b32 %0, %1" : "+v"(x0), "+v"(y0));
                asm volatile("v_permlane32_swap_b32 %0, %1" : "+v"(x1), "+v"(y1));
                union { u32 u[4]; bf16x8 v; } PA;
                PA.u[0] = x0; PA.u[1] = x1; PA.u[2] = y0; PA.u[3] = y1;
                asm("v_cvt_pk_bf16_f32 %0, %1, %2" : "=v"(x0) : "v"(sB[rb+0]), "v"(sB[rb+1]));
                asm("v_cvt_pk_bf16_f32 %0, %1, %2" : "=v"(y0) : "v"(sB[rb+4]), "v"(sB[rb+5]));
                asm("v_cvt_pk_bf16_f32 %0, %1, %2" : "=v"(x1) : "v"(sB[rb+2]), "v"(sB[rb+3]));
                asm("v_cvt_pk_bf16_f32 %0, %1, %2" : "=v"(y1) : "v"(sB[rb+6]), "v"(sB[rb+7]));
                asm volatile("v_permlane32_swap_b32 %0, %1" : "+v"(x0), "+v"(y0));
                asm volatile("v_permlane32_swap_b32 %0, %1" : "+v"(x1), "+v"(y1));
                union { u32 u[4]; bf16x8 v; } PB;
                PB.u[0] = x0; PB.u[1] = x1; PB.u[2] = y0; PB.u[3] = y1;

                const bf16x8 v0 = *(const bf16x8*)(Vb_s + rbase + soff[idx]);
                const bf16x8 v1 = *(const bf16x8*)(Vb_s + 2048 + rbase + soff[idx]);
                __builtin_amdgcn_s_setprio(1);
                o00 = MFMA32(PA.v, v0, o00);
                o01 = MFMA32(PA.v, v1, o01);
                o10 = MFMA32(PB.v, v0, o10);
                o11 = MFMA32(PB.v, v1, o11);
                __builtin_amdgcn_s_setprio(0);
            }
        }
    };

    STAGE(0, 0);
    STAGE(1, 1);

    #pragma unroll 1
    for (int t = 0; t < 31; ++t) {
        // tile t's 4 glds complete (4 newest = tile t+1's stay in flight)
        asm volatile("s_waitcnt vmcnt(4)" ::: "memory");
        __builtin_amdgcn_s_barrier();            // raw: no vmcnt(0) drain
        __builtin_amdgcn_sched_barrier(0);       // no ds_read hoist above barrier
        if (t < 30) STAGE((t + 2) % 3, t + 2);   // 2-deep prefetch
        const u16* Kb_s = sm + (t % 3) * 8192;
        compute_tile(Kb_s, Kb_s + 4096);
    }
    {
        asm volatile("s_waitcnt vmcnt(0)" ::: "memory");
        __builtin_amdgcn_s_barrier();
        __builtin_amdgcn_sched_barrier(0);
        const u16* Kb_s = sm + (31 % 3) * 8192;
        compute_tile(Kb_s, Kb_s + 4096);
    }
#undef STAGE

    // epilogue: L (fp32) and unnormalized bf16 O-half
    lA += __shfl_xor(lA, 32);
    lB += __shfl_xor(lB, 32);
    if (hi == 0) {
        Lp[((size_t)kvh * 16 + bh) * S_LEN + qw + r0]      = lA;
        Lp[((size_t)kvh * 16 + bh) * S_LEN + qw + 32 + r0] = lB;
    }

    u16* Ob = OpB + (size_t)kvh * E_ELEMS + (size_t)b * S_LEN * DMODEL;
    #pragma unroll
    for (int qfi = 0; qfi < 2; ++qfi)
        #pragma unroll
        for (int df = 0; df < 2; ++df) {
            #pragma unroll
            for (int r = 0; r < 16; ++r) {
                const float ov = qfi ? (df ? o11[r] : o10[r]) : (df ? o01[r] : o00[r]);
                const int q = qfi * 32 + (r & 3) + 8 * (r >> 2) + 4 * hi;
                Ob[(size_t)(qw + q) * DMODEL + h * 64 + df * 32 + r0] = f2bf(ov);
            }
        }
}

// ---------------------------------------------------------------------------
// Combine: AO_bf16 = (O_half0 + O_half1) / (L0 + L1)
// ---------------------------------------------------------------------------
__global__ __launch_bounds__(256) void combine_kernel(
    const u16* __restrict__ Op, const float* __restrict__ Lp,
    u16* __restrict__ A)
{
    const int i = blockIdx.x * 256 + threadIdx.x;   // 524288 chunks of 8
    const int m = i >> 6;                           // row 0..8191
    const int col = (i & 63) * 8;
    const int b = m >> 12, s = m & (S_LEN - 1), h = col >> 6;
    const int bh = b * 8 + h;

    const float lt = Lp[(size_t)bh * S_LEN + s] +
                     Lp[((size_t)16 + bh) * S_LEN + s];
    const float inv = 1.0f / lt;

    float acc[8] = {};
    #pragma unroll
    for (int kq = 0; kq < 2; ++kq) {
        const uint4 v = *(const uint4*)(Op + (size_t)kq * E_ELEMS + (size_t)m * DMODEL + col);
        const u16* p = (const u16*)&v;
        #pragma unroll
        for (int j = 0; j < 8; ++j) acc[j] += bf2f(p[j]);
    }
    u16 r[8];
    #pragma unroll
    for (int j = 0; j < 8; ++j) r[j] = f2bf(acc[j] * inv);
    *(uint4*)(A + (size_t)m * DMODEL + col) = *(const uint4*)r;
}

// ---------------------------------------------------------------------------
extern "C" void kernel_launch(void* const* d_in, const int* in_sizes, int n_in,
                              void* d_out, int out_size, void* d_ws, size_t ws_size,
                              hipStream_t stream)
{
    const float* x  = (const float*)d_in[0];
    const float* wq = (const float*)d_in[1];
    const float* bq = (const float*)d_in[2];
    const float* wk = (const float*)d_in[3];
    const float* bk = (const float*)d_in[4];
    const float* wv = (const float*)d_in[5];
    const float* bv = (const float*)d_in[6];
    const float* wo = (const float*)d_in[7];
    const float* bo = (const float*)d_in[8];

    u16* ws = (u16*)d_ws;
    const size_t E = E_ELEMS;
    u16* xbf  = ws;                 // [8192][512]; reused as AO bf16 after combine
    u16* Qbf  = ws + E;             // [bh][s][64]  (pre-scaled)
    u16* Kbf  = ws + 2 * E;         // [bh][s][64]
    u16* Vtbf = ws + 3 * E;         // [bh][64][s]
    u16* wqbf = ws + 4 * E;         // 4 x [512][512]
    u16* wkbf = wqbf + DMODEL * DMODEL;
    u16* wvbf = wkbf + DMODEL * DMODEL;
    u16* wobf = wvbf + DMODEL * DMODEL;
    u16* OpB  = wobf + DMODEL * DMODEL;        // [2][8192][512] bf16 (16.8 MB)
    float* Lp = (float*)(OpB + 2 * E);         // [2][16][4096] f32 (0.5 MB)

    cvt_all<<<dim3(4352), 256, 0, stream>>>(
        x, wq, wk, wv, wo, xbf, wqbf, wkbf, wvbf, wobf);

    proj2_kernel<0><<<dim3(64, 4, 3), 256, 0, stream>>>(
        xbf, wqbf, bq, wkbf, bk, wvbf, bv, Qbf, Kbf, Vtbf, nullptr);

    attn_kernel<<<dim3(512), 256, 0, stream>>>(Qbf, Kbf, Vtbf, OpB, Lp);

    combine_kernel<<<dim3(2048), 256, 0, stream>>>(OpB, Lp, xbf);

    proj2_kernel<1><<<dim3(64, 4, 1), 256, 0, stream>>>(
        xbf, wobf, bo, nullptr, nullptr, nullptr, nullptr,
        nullptr, nullptr, nullptr, (float*)d_out);
}